// Round 1
// baseline (63.421 us; speedup 1.0000x reference)
//
#include <hip/hip_runtime.h>
#include <math.h>

#define EPS 1e-6f

// Input: feat_map [T=32][D=256][H=56][W=56] fp32  (strides: t=802816, d=3136, h=56, w=1)
// ws float layout:
//   [0,    1792)  s1h [32][56]   (direct store, one block per (t,h))
//   [1792, 3584)  s2h [32][56]
//   [3584, 5376)  s1w [32][56]   (global atomic accumulate)
//   [5376, 7168)  s2w [32][56]
// out layout: [0]=tot, [1..1793)=log10(ga1), then ga2, ga3, ga4 (each 32*56)

__global__ __launch_bounds__(448) void loc_reduce(const float* __restrict__ f,
                                                  float* __restrict__ ws) {
    const int b   = blockIdx.x;     // 0..1791
    const int t   = b / 56;
    const int h   = b % 56;
    const int tid = threadIdx.x;    // 0..447
    const int v   = tid % 14;       // float4 column group -> w = 4v..4v+3
    const int dg  = tid / 14;       // 0..31

    const float4* p4 = reinterpret_cast<const float4*>(f + (size_t)t * 802816 + (size_t)h * 56);

    float s10 = 0.f, s11 = 0.f, s12 = 0.f, s13 = 0.f;   // per-w sums of v
    float s20 = 0.f, s21 = 0.f, s22 = 0.f, s23 = 0.f;   // per-w sums of v^2

    #pragma unroll
    for (int i = 0; i < 8; ++i) {
        const int d = dg + 32 * i;
        float4 x = p4[(size_t)d * 784 + v];
        s10 += x.x; s11 += x.y; s12 += x.z; s13 += x.w;
        s20 += x.x * x.x; s21 += x.y * x.y; s22 += x.z * x.z; s23 += x.w * x.w;
    }

    __shared__ float ls1w[56];
    __shared__ float ls2w[56];
    __shared__ float wsum1[7], wsum2[7];

    if (tid < 56) { ls1w[tid] = 0.f; ls2w[tid] = 0.f; }
    __syncthreads();

    // per-w accumulation across the 32 d-groups (LDS atomics, epilogue-only)
    atomicAdd(&ls1w[4 * v + 0], s10);
    atomicAdd(&ls1w[4 * v + 1], s11);
    atomicAdd(&ls1w[4 * v + 2], s12);
    atomicAdd(&ls1w[4 * v + 3], s13);
    atomicAdd(&ls2w[4 * v + 0], s20);
    atomicAdd(&ls2w[4 * v + 1], s21);
    atomicAdd(&ls2w[4 * v + 2], s22);
    atomicAdd(&ls2w[4 * v + 3], s23);

    // per-(t,h) totals: everything this thread read
    float th1 = s10 + s11 + s12 + s13;
    float th2 = s20 + s21 + s22 + s23;
    #pragma unroll
    for (int off = 32; off; off >>= 1) {
        th1 += __shfl_down(th1, off);
        th2 += __shfl_down(th2, off);
    }
    const int wv = tid >> 6, lane = tid & 63;
    if (lane == 0) { wsum1[wv] = th1; wsum2[wv] = th2; }
    __syncthreads();

    if (tid == 0) {
        float a = 0.f, c = 0.f;
        #pragma unroll
        for (int k = 0; k < 7; ++k) { a += wsum1[k]; c += wsum2[k]; }
        ws[t * 56 + h]        = a;
        ws[1792 + t * 56 + h] = c;
    }
    if (tid < 56) {
        atomicAdd(&ws[3584 + t * 56 + tid], ls1w[tid]);
        atomicAdd(&ws[5376 + t * 56 + tid], ls2w[tid]);
    }
}

__global__ __launch_bounds__(64) void loc_finalize(const float* __restrict__ ws,
                                                   float* __restrict__ out) {
    const int tid = threadIdx.x;       // 64 threads: 0..31 H-axis, 32..63 W-axis
    const int t   = tid & 31;
    const bool isW = tid >= 32;

    const float* s1 = ws + (isW ? 3584 : 0)    + t * 56;
    const float* s2 = ws + (isW ? 5376 : 1792) + t * 56;
    float* osuf = out + 1 + (isW ? 3584 : 0)    + t * 56;  // ga1 / ga3
    float* opre = out + 1 + (isW ? 5376 : 1792) + t * 56;  // ga2 / ga4

    const float n_per = 14336.f;   // D*W == D*H == 256*56
    float part = 0.f;

    // suffix (ga1 / ga3)
    float a1 = 0.f, a2 = 0.f;
    for (int i = 55; i >= 0; --i) {
        a1 += s1[i]; a2 += s2[i];
        const float n = n_per * (float)(56 - i);
        const float ga = sqrtf(a2 + 2.0f * EPS * a1 + (EPS * EPS) * n);
        osuf[i] = log10f(ga);
        part += ga + EPS;
    }
    // prefix (ga2 / ga4)
    a1 = 0.f; a2 = 0.f;
    for (int i = 0; i < 56; ++i) {
        a1 += s1[i]; a2 += s2[i];
        const float n = n_per * (float)(i + 1);
        const float ga = sqrtf(a2 + 2.0f * EPS * a1 + (EPS * EPS) * n);
        opre[i] = log10f(ga);
        part += ga + EPS;
    }

    #pragma unroll
    for (int off = 32; off; off >>= 1) part += __shfl_down(part, off);
    if (tid == 0) out[0] = part * (1.0f / 128.0f);   // /(T=32)/(4 variants)
}

extern "C" void kernel_launch(void* const* d_in, const int* in_sizes, int n_in,
                              void* d_out, int out_size, void* d_ws, size_t ws_size,
                              hipStream_t stream) {
    const float* f = (const float*)d_in[0];
    float* out = (float*)d_out;
    float* ws  = (float*)d_ws;

    hipMemsetAsync(d_ws, 0, 7168 * sizeof(float), stream);
    loc_reduce<<<dim3(1792), dim3(448), 0, stream>>>(f, ws);
    loc_finalize<<<dim3(1), dim3(64), 0, stream>>>(ws, out);
}

// Round 2
// 48.145 us; speedup vs baseline: 1.3173x; 1.3173x over previous
//
#include <hip/hip_runtime.h>
#include <math.h>

#define EPS 1e-6f

// Input: feat_map [T=32][D=256][H=56][W=56] fp32 (contiguous; d-slice = 3136 floats = 12.25 KB)
//
// loc_reduce: grid = 32 t * 8 d-groups = 256 blocks, 832 threads (784 active).
//   Each block streams a contiguous 32-d-slice chunk (392 KB). Thread tid<784 has a
//   FIXED (h = tid/14, w-group v = tid%14) position; loops over its 32 d's with
//   register accumulation (4x s1, 4x s2). Epilogue: LDS-atomic reduce to 4x56
//   partials, stored to disjoint ws slots (no global atomics, no memset needed).
//
// ws partials layout: [block=(t*8+dg)][arr(0:s1h,1:s2h,2:s1w,3:s2w)][56]  (57344 floats)
// out layout: [0]=tot, then log10(ga1)[32*56], ga2, ga3, ga4.

__global__ __launch_bounds__(832) void loc_reduce(const float* __restrict__ f,
                                                  float* __restrict__ ws) {
    const int t   = blockIdx.x >> 3;
    const int dg  = blockIdx.x & 7;
    const int tid = threadIdx.x;

    __shared__ float ls[224];  // [arr][56]
    for (int k = tid; k < 224; k += 832) ls[k] = 0.f;
    __syncthreads();

    if (tid < 784) {
        const int h = tid / 14;
        const int v = tid % 14;
        const float4* p4 = reinterpret_cast<const float4*>(
            f + (size_t)t * 802816 + (size_t)(dg * 32) * 3136) + (size_t)h * 14 + v;

        float s10 = 0.f, s11 = 0.f, s12 = 0.f, s13 = 0.f;
        float s20 = 0.f, s21 = 0.f, s22 = 0.f, s23 = 0.f;
        #pragma unroll 4
        for (int d = 0; d < 32; ++d) {
            float4 x = p4[(size_t)d * 784];
            s10 += x.x; s11 += x.y; s12 += x.z; s13 += x.w;
            s20 += x.x * x.x; s21 += x.y * x.y; s22 += x.z * x.z; s23 += x.w * x.w;
        }

        // per-h sums (14-way same-address contention, epilogue-only)
        atomicAdd(&ls[0 * 56 + h], s10 + s11 + s12 + s13);
        atomicAdd(&ls[1 * 56 + h], s20 + s21 + s22 + s23);
        // per-w sums (56-way contention, epilogue-only)
        atomicAdd(&ls[2 * 56 + 4 * v + 0], s10);
        atomicAdd(&ls[2 * 56 + 4 * v + 1], s11);
        atomicAdd(&ls[2 * 56 + 4 * v + 2], s12);
        atomicAdd(&ls[2 * 56 + 4 * v + 3], s13);
        atomicAdd(&ls[3 * 56 + 4 * v + 0], s20);
        atomicAdd(&ls[3 * 56 + 4 * v + 1], s21);
        atomicAdd(&ls[3 * 56 + 4 * v + 2], s22);
        atomicAdd(&ls[3 * 56 + 4 * v + 3], s23);
    }
    __syncthreads();

    if (tid < 224) ws[(size_t)blockIdx.x * 224 + tid] = ls[tid];
}

__global__ __launch_bounds__(1024) void loc_finalize(const float* __restrict__ ws,
                                                     float* __restrict__ out) {
    __shared__ float sums[7168];  // [t][arr][56] = 28 KB
    const int tid = threadIdx.x;

    // Phase 1: reduce the 8 d-group partials (coalesced; 7 outputs/thread).
    #pragma unroll
    for (int k = 0; k < 7; ++k) {
        const int o = tid + 1024 * k;       // o = (t*4 + arr)*56 + i
        const int t = o / 224;
        const int r = o % 224;
        float a = 0.f;
        #pragma unroll
        for (int dg = 0; dg < 8; ++dg) a += ws[(size_t)(t * 8 + dg) * 224 + r];
        sums[o] = a;
    }
    __syncthreads();

    // Phase 2: 64 threads = (t 0..31) x (H-axis / W-axis); serial 56-elem scans.
    if (tid < 64) {
        const int t    = tid & 31;
        const bool isW = tid >= 32;

        const float* s1 = &sums[(t * 4 + (isW ? 2 : 0)) * 56];
        const float* s2 = &sums[(t * 4 + (isW ? 3 : 1)) * 56];
        float* osuf = out + 1 + (isW ? 3584 : 0)    + t * 56;  // ga1 / ga3
        float* opre = out + 1 + (isW ? 5376 : 1792) + t * 56;  // ga2 / ga4

        const float n_per = 14336.f;  // D*W == D*H
        float part = 0.f;

        float a1 = 0.f, a2 = 0.f;
        for (int i = 55; i >= 0; --i) {            // suffix
            a1 += s1[i]; a2 += s2[i];
            const float n  = n_per * (float)(56 - i);
            const float ga = sqrtf(a2 + 2.0f * EPS * a1 + (EPS * EPS) * n);
            osuf[i] = log10f(ga);
            part += ga + EPS;
        }
        a1 = 0.f; a2 = 0.f;
        for (int i = 0; i < 56; ++i) {             // prefix
            a1 += s1[i]; a2 += s2[i];
            const float n  = n_per * (float)(i + 1);
            const float ga = sqrtf(a2 + 2.0f * EPS * a1 + (EPS * EPS) * n);
            opre[i] = log10f(ga);
            part += ga + EPS;
        }

        #pragma unroll
        for (int off = 32; off; off >>= 1) part += __shfl_down(part, off);
        if (tid == 0) out[0] = part * (1.0f / 128.0f);  // /T /4
    }
}

extern "C" void kernel_launch(void* const* d_in, const int* in_sizes, int n_in,
                              void* d_out, int out_size, void* d_ws, size_t ws_size,
                              hipStream_t stream) {
    const float* f = (const float*)d_in[0];
    float* out = (float*)d_out;
    float* ws  = (float*)d_ws;

    loc_reduce<<<dim3(256), dim3(832), 0, stream>>>(f, ws);
    loc_finalize<<<dim3(1), dim3(1024), 0, stream>>>(ws, out);
}